// Round 11
// baseline (2082.422 us; speedup 1.0000x reference)
//
#include <hip/hip_runtime.h>
#include <math.h>

// Problem constants (match reference)
#define B   64
#define C   256
#define CR  16
#define HW  3136          // 56*56 floats = 12.25 KB per plane
#define INV_HW (1.0f / 3136.0f)

typedef float vf4 __attribute__((ext_vector_type(4)));

// ---------------------------------------------------------------------------
// Single-pass SE: one block per (b,c) plane, 256 threads.
//  1. load the whole plane into registers (784 float4 across 256 threads)
//  2. reduce -> mean; publish pooled[plane] (agent-scope release) and
//     increment cnt[b]; thread 0 spins until all 256 blocks of row b arrived
//  3. read pooled row (agent-scope loads, L1-bypassing), compute the gate
//  4. scale the REGISTER-RESIDENT plane and store non-temporally.
// Input is read exactly once: 205 MB read + 205 MB write total traffic.
// Forward progress: every block publishes before spinning; resident capacity
// (~8 blocks/CU x 256 CU = 2048) >> one row (256 contiguous block ids), and
// the CP dispatches ids monotonically, so spinning rows always complete.
// ---------------------------------------------------------------------------
__global__ __launch_bounds__(256) void se_onepass(const float* __restrict__ in,
                                                  const float* __restrict__ w1,
                                                  const float* __restrict__ b1,
                                                  const float* __restrict__ w2,
                                                  const float* __restrict__ b2,
                                                  float* __restrict__ pooled,
                                                  int* __restrict__ cnt,
                                                  float* __restrict__ out) {
    const int plane = blockIdx.x;      // b*C + c
    const int b = plane >> 8;
    const int c = plane & (C - 1);
    const int t = threadIdx.x;

    const vf4* pi = reinterpret_cast<const vf4*>(in + (size_t)plane * HW);
    vf4* po = reinterpret_cast<vf4*>(out + (size_t)plane * HW);

    // --- 1. whole plane -> registers (784 = 3*256 + 16 float4) ---
    vf4 r0 = pi[t];
    vf4 r1 = pi[t + 256];
    vf4 r2 = pi[t + 512];
    vf4 r3;
    const bool has4 = (t < 16);
    if (has4) r3 = pi[t + 768];

    // --- 2. pool from registers ---
    float s = (r0.x + r0.y) + (r0.z + r0.w)
            + (r1.x + r1.y) + (r1.z + r1.w)
            + (r2.x + r2.y) + (r2.z + r2.w);
    if (has4) s += (r3.x + r3.y) + (r3.z + r3.w);

    #pragma unroll
    for (int off = 32; off > 0; off >>= 1)
        s += __shfl_down(s, off, 64);

    __shared__ float wsum[4];
    __shared__ float sp[C];
    __shared__ float sh[CR];
    __shared__ float sg;

    const int lane = t & 63, wid = t >> 6;
    if (lane == 0) wsum[wid] = s;
    __syncthreads();

    if (t == 0) {
        float mean = ((wsum[0] + wsum[1]) + (wsum[2] + wsum[3])) * INV_HW;
        __hip_atomic_store(&pooled[plane], mean, __ATOMIC_RELEASE,
                           __HIP_MEMORY_SCOPE_AGENT);
        __hip_atomic_fetch_add(&cnt[b], 1, __ATOMIC_ACQ_REL,
                               __HIP_MEMORY_SCOPE_AGENT);
        // spin until the whole batch row is pooled
        while (__hip_atomic_load(&cnt[b], __ATOMIC_ACQUIRE,
                                 __HIP_MEMORY_SCOPE_AGENT) < C)
            __builtin_amdgcn_s_sleep(2);
    }
    __syncthreads();

    // --- 3. gate for channel c (agent-scope loads: fresh, L1-bypassing) ---
    sp[t] = __hip_atomic_load(&pooled[b * C + t], __ATOMIC_RELAXED,
                              __HIP_MEMORY_SCOPE_AGENT);
    __syncthreads();

    if (t < CR) {
        float acc = b1[t];
        const float* wrow = w1 + t * C;       // w1 is [CR, C]
        #pragma unroll 8
        for (int k = 0; k < C; ++k) acc = fmaf(sp[k], wrow[k], acc);
        sh[t] = fmaxf(acc, 0.f);
    }
    __syncthreads();

    if (t == 0) {
        float acc = b2[c];
        const float* wrow = w2 + c * CR;      // w2 is [C, CR]
        #pragma unroll
        for (int k = 0; k < CR; ++k) acc = fmaf(sh[k], wrow[k], acc);
        sg = 1.0f / (1.0f + expf(-acc));
    }
    __syncthreads();
    const float g = sg;

    // --- 4. scale register-resident plane, non-temporal store ---
    r0 *= g; r1 *= g; r2 *= g;
    __builtin_nontemporal_store(r0, po + t);
    __builtin_nontemporal_store(r1, po + t + 256);
    __builtin_nontemporal_store(r2, po + t + 512);
    if (has4) {
        r3 *= g;
        __builtin_nontemporal_store(r3, po + t + 768);
    }
}

extern "C" void kernel_launch(void* const* d_in, const int* in_sizes, int n_in,
                              void* d_out, int out_size, void* d_ws, size_t ws_size,
                              hipStream_t stream) {
    const float* feat = (const float*)d_in[0];
    const float* w1   = (const float*)d_in[1];
    const float* b1   = (const float*)d_in[2];
    const float* w2   = (const float*)d_in[3];
    const float* b2   = (const float*)d_in[4];
    float* out = (float*)d_out;

    float* pooled = (float*)d_ws;            // B*C floats
    int*   cnt    = (int*)(pooled + B * C);  // B ints, must start at 0

    // d_ws is poisoned 0xAA before every timed launch -> zero the semaphores.
    hipMemsetAsync(cnt, 0, B * sizeof(int), stream);

    se_onepass<<<B * C, 256, 0, stream>>>(feat, w1, b1, w2, b2, pooled, cnt, out);
}

// Round 12
// 1268.983 us; speedup vs baseline: 1.6410x; 1.6410x over previous
//
#include <hip/hip_runtime.h>
#include <math.h>

// Problem constants (match reference)
#define B   64
#define C   256
#define CR  16
#define HW  3136          // 56*56 floats = 12.25 KB per plane
#define INV_HW (1.0f / 3136.0f)

typedef float vf4 __attribute__((ext_vector_type(4)));

// ---------------------------------------------------------------------------
// Kernel 1: pool every (b,c) plane; the LAST block of each batch row (found
// via agent-scope counter, no spinning) computes the row's full gate vector:
//   gate[b,:] = sigmoid(relu(pooled[b,:] @ w1^T + b1) @ w2^T + b2)
// Gate work: hidden units computed by all 256 threads (16 lanes per unit,
// 16-wide shfl reduce); then thread t computes channel t's gate.
// ---------------------------------------------------------------------------
__global__ __launch_bounds__(256) void se_pool_gate(const float* __restrict__ in,
                                                    const float* __restrict__ w1,
                                                    const float* __restrict__ b1,
                                                    const float* __restrict__ w2,
                                                    const float* __restrict__ b2,
                                                    float* __restrict__ pooled,
                                                    int* __restrict__ cnt,
                                                    float* __restrict__ gate) {
    const int plane = blockIdx.x;      // b*C + c
    const int b = plane >> 8;
    const int t = threadIdx.x;

    const vf4* p = reinterpret_cast<const vf4*>(in + (size_t)plane * HW);

    // --- pool this plane (784 float4 = 3*256 + 16) ---
    float s;
    {
        vf4 v0 = p[t];
        vf4 v1 = p[t + 256];
        vf4 v2 = p[t + 512];
        s = (v0.x + v0.y) + (v0.z + v0.w)
          + (v1.x + v1.y) + (v1.z + v1.w)
          + (v2.x + v2.y) + (v2.z + v2.w);
        if (t < 16) {
            vf4 v3 = p[t + 768];
            s += (v3.x + v3.y) + (v3.z + v3.w);
        }
    }
    #pragma unroll
    for (int off = 32; off > 0; off >>= 1)
        s += __shfl_down(s, off, 64);

    __shared__ float wsum[4];
    __shared__ int   lastFlag;
    const int lane = t & 63, wid = t >> 6;
    if (lane == 0) wsum[wid] = s;
    __syncthreads();

    if (t == 0) {
        float mean = ((wsum[0] + wsum[1]) + (wsum[2] + wsum[3])) * INV_HW;
        __hip_atomic_store(&pooled[plane], mean, __ATOMIC_RELEASE,
                           __HIP_MEMORY_SCOPE_AGENT);
        int old = __hip_atomic_fetch_add(&cnt[b], 1, __ATOMIC_ACQ_REL,
                                         __HIP_MEMORY_SCOPE_AGENT);
        lastFlag = (old == C - 1);
    }
    __syncthreads();
    if (!lastFlag) return;

    // --- last block of row b: compute the whole gate row ---
    __shared__ float sp[C];
    __shared__ float sh[CR];

    sp[t] = __hip_atomic_load(&pooled[b * C + t], __ATOMIC_ACQUIRE,
                              __HIP_MEMORY_SCOPE_AGENT);
    __syncthreads();

    {   // hidden unit hu = t>>4, chunk ch = t&15 (16 elems), 16-wide reduce
        const int hu = t >> 4, ch = t & 15;
        const float* wr = w1 + hu * C + ch * 16;   // w1 is [CR, C]
        const float* sr = sp + ch * 16;
        float part = 0.f;
        #pragma unroll
        for (int i = 0; i < 16; ++i) part = fmaf(sr[i], wr[i], part);
        #pragma unroll
        for (int off = 8; off > 0; off >>= 1)
            part += __shfl_down(part, off, 16);
        if (ch == 0) sh[hu] = fmaxf(part + b1[hu], 0.f);
    }
    __syncthreads();

    {   // channel t's gate
        float acc = b2[t];
        const float* wr = w2 + t * CR;             // w2 is [C, CR]
        #pragma unroll
        for (int k = 0; k < CR; ++k) acc = fmaf(sh[k], wr[k], acc);
        gate[b * C + t] = 1.0f / (1.0f + expf(-acc));
    }
}

// ---------------------------------------------------------------------------
// Kernel 2: pure streaming rescale. One block per plane; one scalar gate
// load; float4 loads (L3-hot from kernel 1) + non-temporal stores.
// ---------------------------------------------------------------------------
__global__ __launch_bounds__(256) void se_scale2(const float* __restrict__ in,
                                                 const float* __restrict__ gate,
                                                 float* __restrict__ out) {
    const int plane = blockIdx.x;
    const int t = threadIdx.x;
    const float g = gate[plane];

    const vf4* pi = reinterpret_cast<const vf4*>(in + (size_t)plane * HW);
    vf4* po = reinterpret_cast<vf4*>(out + (size_t)plane * HW);

    vf4 r0 = pi[t];
    vf4 r1 = pi[t + 256];
    vf4 r2 = pi[t + 512];
    r0 *= g; r1 *= g; r2 *= g;
    __builtin_nontemporal_store(r0, po + t);
    __builtin_nontemporal_store(r1, po + t + 256);
    __builtin_nontemporal_store(r2, po + t + 512);
    if (t < 16) {
        vf4 r3 = pi[t + 768];
        r3 *= g;
        __builtin_nontemporal_store(r3, po + t + 768);
    }
}

extern "C" void kernel_launch(void* const* d_in, const int* in_sizes, int n_in,
                              void* d_out, int out_size, void* d_ws, size_t ws_size,
                              hipStream_t stream) {
    const float* feat = (const float*)d_in[0];
    const float* w1   = (const float*)d_in[1];
    const float* b1   = (const float*)d_in[2];
    const float* w2   = (const float*)d_in[3];
    const float* b2   = (const float*)d_in[4];
    float* out = (float*)d_out;

    float* pooled = (float*)d_ws;                  // B*C floats (64 KiB)
    int*   cnt    = (int*)(pooled + B * C);        // B ints
    float* gate   = (float*)(cnt + 64);            // B*C floats (64-int pad)

    // d_ws is re-poisoned 0xAA before every timed launch -> zero the counters.
    hipMemsetAsync(cnt, 0, B * sizeof(int), stream);

    se_pool_gate<<<B * C, 256, 0, stream>>>(feat, w1, b1, w2, b2, pooled, cnt, gate);
    se_scale2  <<<B * C, 256, 0, stream>>>(feat, gate, out);
}